// Round 1
// baseline (404.832 us; speedup 1.0000x reference)
//
#include <hip/hip_runtime.h>

// CausalSelfAttention: B=4, T=2048, C=1024, H=16, HD=64
// Pipeline: x->bf16 | W->bf16^T | QKV GEMM (bf16 MFMA) | flash attn | proj GEMM

typedef __attribute__((ext_vector_type(8))) short bf16x8;
typedef __attribute__((ext_vector_type(4))) float f32x4;
typedef __attribute__((ext_vector_type(4))) int int4v;

#define B_ 4
#define T_ 2048
#define C_ 1024
#define H_ 16
#define HD_ 64

__device__ __forceinline__ unsigned short f2bf(float f) {
    union { float f; unsigned u; } c; c.f = f;
    unsigned u = c.u;
    u = u + 0x7FFFu + ((u >> 16) & 1u);   // RNE
    return (unsigned short)(u >> 16);
}

// ---------------- x f32 -> bf16 ----------------
__global__ __launch_bounds__(256) void k_conv(const float* __restrict__ in,
                                              unsigned short* __restrict__ out, int n) {
    int i = (blockIdx.x * 256 + threadIdx.x) * 4;
    if (i >= n) return;
    float4 v = *(const float4*)(in + i);
    unsigned short r[4] = { f2bf(v.x), f2bf(v.y), f2bf(v.z), f2bf(v.w) };
    *(unsigned long long*)(out + i) = *(const unsigned long long*)r;
}

// ---------------- W [R][Cin] f32 -> out [Cin][R] bf16 (transpose+convert) ----------------
__global__ __launch_bounds__(256) void k_transp(const float* __restrict__ in,
                                                unsigned short* __restrict__ out,
                                                int R, int Cin) {
    __shared__ float t[32][33];
    int bx = blockIdx.x, by = blockIdx.y;
    int j = threadIdx.x & 31, i0 = threadIdx.x >> 5;
#pragma unroll
    for (int k = 0; k < 4; k++) {
        int i = i0 + k * 8;
        t[i][j] = in[(size_t)(by * 32 + i) * Cin + bx * 32 + j];
    }
    __syncthreads();
#pragma unroll
    for (int k = 0; k < 4; k++) {
        int c = i0 + k * 8;
        out[(size_t)(bx * 32 + c) * R + by * 32 + j] = f2bf(t[j][c]);
    }
}

// ---------------- GEMM: D[M][N] = A[M][K] * BT[N][K]^T + bias ----------------
// MODE 0: scatter to Q/K/V bf16 [B,H,T,64].  MODE 1: f32 out [M][N].
template<int MODE>
__global__ __launch_bounds__(256) void k_gemm(
    const unsigned short* __restrict__ A, const unsigned short* __restrict__ BT,
    const float* __restrict__ bias,
    unsigned short* __restrict__ Qb, unsigned short* __restrict__ Kb,
    unsigned short* __restrict__ Vb,
    float* __restrict__ out, int M, int N, int K)
{
    __shared__ unsigned short As[128][40];   // +8 pad -> 80B row stride (16B aligned, 2-way banks)
    __shared__ unsigned short Bs[128][40];
    const int tid = threadIdx.x;
    const int lane = tid & 63;
    const int wv = tid >> 6;
    const int wm = wv >> 1, wn = wv & 1;
    const int l15 = lane & 15, lg = lane >> 4;
    const int bm = blockIdx.y * 128, bn = blockIdx.x * 128;

    f32x4 acc[4][4];
#pragma unroll
    for (int m = 0; m < 4; m++)
#pragma unroll
        for (int n = 0; n < 4; n++) acc[m][n] = (f32x4){0.f, 0.f, 0.f, 0.f};

    const int sr = tid >> 2;            // 0..63
    const int sc = (tid & 3) * 8;       // 0,8,16,24

    for (int k0 = 0; k0 < K; k0 += 32) {
#pragma unroll
        for (int rr = 0; rr < 128; rr += 64) {
            *(int4v*)(&As[sr + rr][sc]) = *(const int4v*)(&A[(size_t)(bm + sr + rr) * K + k0 + sc]);
            *(int4v*)(&Bs[sr + rr][sc]) = *(const int4v*)(&BT[(size_t)(bn + sr + rr) * K + k0 + sc]);
        }
        __syncthreads();
        bf16x8 af[4], bfr[4];
#pragma unroll
        for (int m = 0; m < 4; m++) af[m]  = *(const bf16x8*)(&As[wm * 64 + m * 16 + l15][lg * 8]);
#pragma unroll
        for (int n = 0; n < 4; n++) bfr[n] = *(const bf16x8*)(&Bs[wn * 64 + n * 16 + l15][lg * 8]);
#pragma unroll
        for (int m = 0; m < 4; m++)
#pragma unroll
            for (int n = 0; n < 4; n++)
                acc[m][n] = __builtin_amdgcn_mfma_f32_16x16x32_bf16(af[m], bfr[n], acc[m][n], 0, 0, 0);
        __syncthreads();
    }

#pragma unroll
    for (int m = 0; m < 4; m++) {
#pragma unroll
        for (int n = 0; n < 4; n++) {
            int col = bn + wn * 64 + n * 16 + l15;
            float bval = bias[col];
#pragma unroll
            for (int r = 0; r < 4; r++) {
                int row = bm + wm * 64 + m * 16 + lg * 4 + r;
                float v = acc[m][n][r] + bval;
                if (MODE == 0) {
                    int b = row >> 11, t = row & 2047;
                    int which = col >> 10;
                    int h = (col & 1023) >> 6, d = col & 63;
                    unsigned short* dst = (which == 0) ? Qb : (which == 1) ? Kb : Vb;
                    dst[(((size_t)(b * 16 + h) * 2048) + t) * 64 + d] = f2bf(v);
                } else {
                    out[(size_t)row * N + col] = v;
                }
            }
        }
    }
}

// ---------------- Flash attention (causal), Q/K/V bf16 [B*H, T, 64] ----------------
__global__ __launch_bounds__(256) void k_attn(
    const unsigned short* __restrict__ Qb, const unsigned short* __restrict__ Kb,
    const unsigned short* __restrict__ Vb, unsigned short* __restrict__ att)
{
    __shared__ unsigned short Ks[64][72];       // [key][d], pad 8 -> 144B stride
    __shared__ unsigned short Vs[64][72];       // transposed: [d][key]
    __shared__ unsigned short Ps[4][16][72];    // per-wave P tile [qrow][key]

    const int tid = threadIdx.x, lane = tid & 63, w = tid >> 6;
    const int l15 = lane & 15, lg = lane >> 4;
    const int qt = blockIdx.x;       // 0..31
    const int bh = blockIdx.y;       // 0..63
    const int b = bh >> 4, h = bh & 15;
    const int qb = qt * 64;
    const size_t base = (size_t)bh * T_ * HD_;

    // Q fragments (A-layout): row = l15 within wave's 16-row tile
    const int qrowA = qb + w * 16 + l15;
    bf16x8 qf[2];
#pragma unroll
    for (int s = 0; s < 2; s++)
        qf[s] = *(const bf16x8*)(Qb + base + (size_t)qrowA * HD_ + s * 32 + lg * 8);

    float mrow[4], lrow[4];
    f32x4 o[4];
#pragma unroll
    for (int r = 0; r < 4; r++) { mrow[r] = -1e30f; lrow[r] = 0.f; }
#pragma unroll
    for (int c = 0; c < 4; c++) o[c] = (f32x4){0.f, 0.f, 0.f, 0.f};

    const int qrowD = qb + w * 16 + lg * 4;   // + r (D-layout row)

    for (int kt = 0; kt <= qt; ++kt) {
        // stage K tile and transposed V tile
#pragma unroll
        for (int i = 0; i < 2; i++) {
            int ch = tid * 2 + i;                 // 0..511
            int key = ch >> 3, c8 = (ch & 7) * 8;
            const size_t g = base + (size_t)(kt * 64 + key) * HD_ + c8;
            *(int4v*)(&Ks[key][c8]) = *(const int4v*)(Kb + g);
            int4v vv = *(const int4v*)(Vb + g);
            const unsigned short* vp = (const unsigned short*)&vv;
#pragma unroll
            for (int j = 0; j < 8; j++) Vs[c8 + j][key] = vp[j];
        }
        __syncthreads();

        // S = Q K^T  (per wave: 16 q-rows x 64 keys)
        float sv[4][4];
#pragma unroll
        for (int c = 0; c < 4; c++) {
            f32x4 s4 = (f32x4){0.f, 0.f, 0.f, 0.f};
#pragma unroll
            for (int s = 0; s < 2; s++) {
                bf16x8 kf = *(const bf16x8*)(&Ks[c * 16 + l15][s * 32 + lg * 8]);
                s4 = __builtin_amdgcn_mfma_f32_16x16x32_bf16(qf[s], kf, s4, 0, 0, 0);
            }
            int col = kt * 64 + c * 16 + l15;
#pragma unroll
            for (int r = 0; r < 4; r++) {
                float xx = s4[r] * 0.18033688011112042f;   // 0.125 * log2(e)
                int row = qrowD + r;
                sv[c][r] = (col > row) ? -1e30f : xx;
            }
        }

        // online softmax (16-lane group reduce)
#pragma unroll
        for (int r = 0; r < 4; r++) {
            float tm = fmaxf(fmaxf(sv[0][r], sv[1][r]), fmaxf(sv[2][r], sv[3][r]));
#pragma unroll
            for (int d = 1; d < 16; d <<= 1) tm = fmaxf(tm, __shfl_xor(tm, d));
            float mn = fmaxf(mrow[r], tm);
            float alpha = exp2f(mrow[r] - mn);
            mrow[r] = mn;
            float ps = 0.f;
#pragma unroll
            for (int c = 0; c < 4; c++) {
                float pv = exp2f(sv[c][r] - mn);
                sv[c][r] = pv;
                ps += pv;
            }
#pragma unroll
            for (int d = 1; d < 16; d <<= 1) ps += __shfl_xor(ps, d);
            lrow[r] = lrow[r] * alpha + ps;
#pragma unroll
            for (int c = 0; c < 4; c++) o[c][r] *= alpha;
        }

        // P -> LDS (wave-local region; compiler orders ds_write->ds_read via lgkmcnt)
#pragma unroll
        for (int c = 0; c < 4; c++)
#pragma unroll
            for (int r = 0; r < 4; r++)
                Ps[w][lg * 4 + r][c * 16 + l15] = f2bf(sv[c][r]);

        // O += P V
        bf16x8 pf[2];
#pragma unroll
        for (int s = 0; s < 2; s++)
            pf[s] = *(const bf16x8*)(&Ps[w][l15][s * 32 + lg * 8]);
#pragma unroll
        for (int cd = 0; cd < 4; cd++) {
#pragma unroll
            for (int s = 0; s < 2; s++) {
                bf16x8 vf = *(const bf16x8*)(&Vs[cd * 16 + l15][s * 32 + lg * 8]);
                o[cd] = __builtin_amdgcn_mfma_f32_16x16x32_bf16(pf[s], vf, o[cd], 0, 0, 0);
            }
        }
        __syncthreads();
    }

    // epilogue: normalize and write att [B*T][C] bf16
#pragma unroll
    for (int cd = 0; cd < 4; cd++) {
#pragma unroll
        for (int r = 0; r < 4; r++) {
            int trow = qrowD + r;
            int col = h * 64 + cd * 16 + l15;
            float v = o[cd][r] / lrow[r];
            att[((size_t)(b * 2048 + trow)) * 1024 + col] = f2bf(v);
        }
    }
}

extern "C" void kernel_launch(void* const* d_in, const int* in_sizes, int n_in,
                              void* d_out, int out_size, void* d_ws, size_t ws_size,
                              hipStream_t stream)
{
    const float* x      = (const float*)d_in[0];
    const float* W_qkv  = (const float*)d_in[1];
    const float* b_qkv  = (const float*)d_in[2];
    const float* W_proj = (const float*)d_in[3];
    const float* b_proj = (const float*)d_in[4];
    float* out = (float*)d_out;

    char* p = (char*)d_ws;
    unsigned short* xbf    = (unsigned short*)p; p += (size_t)8192 * 1024 * 2;  // reused as att out
    unsigned short* wqkvT  = (unsigned short*)p; p += (size_t)3072 * 1024 * 2;
    unsigned short* wprojT = (unsigned short*)p; p += (size_t)1024 * 1024 * 2;
    unsigned short* Qb     = (unsigned short*)p; p += (size_t)8192 * 1024 * 2;
    unsigned short* Kb     = (unsigned short*)p; p += (size_t)8192 * 1024 * 2;
    unsigned short* Vb     = (unsigned short*)p; p += (size_t)8192 * 1024 * 2;
    // total: 75.5 MB

    k_conv<<<8192, 256, 0, stream>>>(x, xbf, 8192 * 1024);
    k_transp<<<dim3(96, 32), 256, 0, stream>>>(W_qkv, wqkvT, 1024, 3072);
    k_transp<<<dim3(32, 32), 256, 0, stream>>>(W_proj, wprojT, 1024, 1024);
    k_gemm<0><<<dim3(24, 64), 256, 0, stream>>>(xbf, wqkvT, b_qkv, Qb, Kb, Vb, nullptr, 8192, 3072, 1024);
    k_attn<<<dim3(32, 64), 256, 0, stream>>>(Qb, Kb, Vb, xbf);
    k_gemm<1><<<dim3(8, 64), 256, 0, stream>>>(xbf, wprojT, b_proj, nullptr, nullptr, nullptr, out, 8192, 1024, 1024);
}

// Round 2
// 358.979 us; speedup vs baseline: 1.1277x; 1.1277x over previous
//
#include <hip/hip_runtime.h>

// CausalSelfAttention: B=4, T=2048, C=1024, H=16, HD=64
// Pipeline: x->bf16 | W->bf16^T | QKV GEMM (bf16 MFMA, V written transposed) |
//           flash attn (128-row q-tiles, prefetch) | proj GEMM

typedef __attribute__((ext_vector_type(8))) short bf16x8;
typedef __attribute__((ext_vector_type(4))) float f32x4;
typedef __attribute__((ext_vector_type(4))) int int4v;

#define B_ 4
#define T_ 2048
#define C_ 1024
#define H_ 16
#define HD_ 64
#define SCALE_LOG2E 0.18033688011112042f   // (1/8) * log2(e)

__device__ __forceinline__ unsigned short f2bf(float f) {
    union { float f; unsigned u; } c; c.f = f;
    unsigned u = c.u;
    u = u + 0x7FFFu + ((u >> 16) & 1u);   // RNE
    return (unsigned short)(u >> 16);
}

// ---------------- x f32 -> bf16 ----------------
__global__ __launch_bounds__(256) void k_conv(const float* __restrict__ in,
                                              unsigned short* __restrict__ out, int n) {
    int i = (blockIdx.x * 256 + threadIdx.x) * 4;
    if (i >= n) return;
    float4 v = *(const float4*)(in + i);
    unsigned short r[4] = { f2bf(v.x), f2bf(v.y), f2bf(v.z), f2bf(v.w) };
    *(unsigned long long*)(out + i) = *(const unsigned long long*)r;
}

// ---------------- W [R][Cin] f32 -> out [Cin][R] bf16 (transpose+convert) ----------------
__global__ __launch_bounds__(256) void k_transp(const float* __restrict__ in,
                                                unsigned short* __restrict__ out,
                                                int R, int Cin) {
    __shared__ float t[32][33];
    int bx = blockIdx.x, by = blockIdx.y;
    int j = threadIdx.x & 31, i0 = threadIdx.x >> 5;
#pragma unroll
    for (int k = 0; k < 4; k++) {
        int i = i0 + k * 8;
        t[i][j] = in[(size_t)(by * 32 + i) * Cin + bx * 32 + j];
    }
    __syncthreads();
#pragma unroll
    for (int k = 0; k < 4; k++) {
        int c = i0 + k * 8;
        out[(size_t)(bx * 32 + c) * R + by * 32 + j] = f2bf(t[j][c]);
    }
}

// ---------------- GEMM: D[M][N] = A[M][K] * BT[N][K]^T + bias ----------------
// MODE 0: scatter Q/K bf16 [B,H,T,64], V transposed -> Vt [B,H,64,T].  MODE 1: f32 out [M][N].
template<int MODE>
__global__ __launch_bounds__(256) void k_gemm(
    const unsigned short* __restrict__ A, const unsigned short* __restrict__ BT,
    const float* __restrict__ bias,
    unsigned short* __restrict__ Qb, unsigned short* __restrict__ Kb,
    unsigned short* __restrict__ Vt,
    float* __restrict__ out, int M, int N, int K)
{
    __shared__ unsigned short As[128][40];   // 80B row stride (16B aligned)
    __shared__ unsigned short Bs[128][40];
    const int tid = threadIdx.x;
    const int lane = tid & 63;
    const int wv = tid >> 6;
    const int wm = wv >> 1, wn = wv & 1;
    const int l15 = lane & 15, lg = lane >> 4;
    const int bm = blockIdx.y * 128, bn = blockIdx.x * 128;

    f32x4 acc[4][4];
#pragma unroll
    for (int m = 0; m < 4; m++)
#pragma unroll
        for (int n = 0; n < 4; n++) acc[m][n] = (f32x4){0.f, 0.f, 0.f, 0.f};

    const int sr = tid >> 2;
    const int sc = (tid & 3) * 8;

    for (int k0 = 0; k0 < K; k0 += 32) {
#pragma unroll
        for (int rr = 0; rr < 128; rr += 64) {
            *(int4v*)(&As[sr + rr][sc]) = *(const int4v*)(&A[(size_t)(bm + sr + rr) * K + k0 + sc]);
            *(int4v*)(&Bs[sr + rr][sc]) = *(const int4v*)(&BT[(size_t)(bn + sr + rr) * K + k0 + sc]);
        }
        __syncthreads();
        bf16x8 af[4], bfr[4];
#pragma unroll
        for (int m = 0; m < 4; m++) af[m]  = *(const bf16x8*)(&As[wm * 64 + m * 16 + l15][lg * 8]);
#pragma unroll
        for (int n = 0; n < 4; n++) bfr[n] = *(const bf16x8*)(&Bs[wn * 64 + n * 16 + l15][lg * 8]);
#pragma unroll
        for (int m = 0; m < 4; m++)
#pragma unroll
            for (int n = 0; n < 4; n++)
                acc[m][n] = __builtin_amdgcn_mfma_f32_16x16x32_bf16(af[m], bfr[n], acc[m][n], 0, 0, 0);
        __syncthreads();
    }

#pragma unroll
    for (int m = 0; m < 4; m++) {
#pragma unroll
        for (int n = 0; n < 4; n++) {
            int col = bn + wn * 64 + n * 16 + l15;
            float bval = bias[col];
            int row0 = bm + wm * 64 + m * 16 + lg * 4;
            float vals[4];
#pragma unroll
            for (int r = 0; r < 4; r++) vals[r] = acc[m][n][r] + bval;
            if (MODE == 1) {
#pragma unroll
                for (int r = 0; r < 4; r++) out[(size_t)(row0 + r) * N + col] = vals[r];
            } else {
                int b = row0 >> 11, t0 = row0 & 2047;
                int which = col >> 10;
                int h = (col & 1023) >> 6, d = col & 63;
                if (which == 2) {
                    unsigned short pk[4];
#pragma unroll
                    for (int r = 0; r < 4; r++) pk[r] = f2bf(vals[r]);
                    *(unsigned long long*)(&Vt[((size_t)(b * H_ + h) * HD_ + d) * T_ + t0]) =
                        *(const unsigned long long*)pk;
                } else {
                    unsigned short* dst = which ? Kb : Qb;
#pragma unroll
                    for (int r = 0; r < 4; r++)
                        dst[((size_t)(b * H_ + h) * T_ + t0 + r) * HD_ + d] = f2bf(vals[r]);
                }
            }
        }
    }
}

// ---------------- Flash attention (causal) ----------------
// Q,K: [B*H, T, 64].  Vt: [B*H, 64, T].  128 q-rows per block (32 per wave).
__global__ __launch_bounds__(256) void k_attn(
    const unsigned short* __restrict__ Qb, const unsigned short* __restrict__ Kb,
    const unsigned short* __restrict__ Vt, unsigned short* __restrict__ att)
{
    __shared__ unsigned short Ks[64][72];       // [key][d]
    __shared__ unsigned short Vs[64][72];       // [d][key]  (straight copy from Vt)
    __shared__ unsigned short Ps[4][32][72];    // per-wave P tile [qrow][key]

    const int tid = threadIdx.x, lane = tid & 63, w = tid >> 6;
    const int l15 = lane & 15, lg = lane >> 4;
    const int qt = 15 - (int)blockIdx.x;        // longest-first
    const int bh = blockIdx.y;
    const int b = bh >> 4, h = bh & 15;
    const int qb = qt * 128;
    const size_t kqbase = (size_t)bh * T_ * HD_;
    const size_t vtbase = (size_t)bh * HD_ * T_;

    // Q fragments: wave w owns rows qb+w*32 .. +31 (m=0,1 subtiles of 16)
    bf16x8 qf[2][2];
#pragma unroll
    for (int m = 0; m < 2; m++)
#pragma unroll
        for (int s = 0; s < 2; s++)
            qf[m][s] = *(const bf16x8*)(Qb + kqbase +
                        (size_t)(qb + w * 32 + m * 16 + l15) * HD_ + s * 32 + lg * 8);

    f32x4 o[2][4];
    float mrow[2][4], lpart[2][4];
#pragma unroll
    for (int m = 0; m < 2; m++) {
#pragma unroll
        for (int r = 0; r < 4; r++) { mrow[m][r] = -1e30f; lpart[m][r] = 0.f; }
#pragma unroll
        for (int c = 0; c < 4; c++) o[m][c] = (f32x4){0.f, 0.f, 0.f, 0.f};
    }

    const int last = 2 * qt + 1;
    const int r0 = tid >> 3;          // 0..31
    const int c8 = (tid & 7) * 8;

    // prefetch tile 0 into registers
    int4v kreg[2], vreg[2];
#pragma unroll
    for (int i = 0; i < 2; i++) {
        kreg[i] = *(const int4v*)(Kb + kqbase + (size_t)(r0 + i * 32) * HD_ + c8);
        vreg[i] = *(const int4v*)(Vt + vtbase + (size_t)(r0 + i * 32) * T_ + c8);
    }

    for (int kt = 0; kt <= last; ++kt) {
        __syncthreads();                    // previous tile's LDS consumers done
#pragma unroll
        for (int i = 0; i < 2; i++) {
            *(int4v*)(&Ks[r0 + i * 32][c8]) = kreg[i];
            *(int4v*)(&Vs[r0 + i * 32][c8]) = vreg[i];
        }
        if (kt < last) {                    // issue next tile's loads early (T14)
            int nk = (kt + 1) * 64;
#pragma unroll
            for (int i = 0; i < 2; i++) {
                kreg[i] = *(const int4v*)(Kb + kqbase + (size_t)(nk + r0 + i * 32) * HD_ + c8);
                vreg[i] = *(const int4v*)(Vt + vtbase + (size_t)(r0 + i * 32) * T_ + nk + c8);
            }
        }
        __syncthreads();                    // LDS tile ready

        // wave active iff its 32 rows are all >= first key of this tile
        if (qb + w * 32 + 31 >= kt * 64) {
            float sv[2][4][4];
#pragma unroll
            for (int c = 0; c < 4; c++) {
                bf16x8 kf0 = *(const bf16x8*)(&Ks[c * 16 + l15][lg * 8]);
                bf16x8 kf1 = *(const bf16x8*)(&Ks[c * 16 + l15][32 + lg * 8]);
                int col = kt * 64 + c * 16 + l15;
#pragma unroll
                for (int m = 0; m < 2; m++) {
                    f32x4 s4 = (f32x4){0.f, 0.f, 0.f, 0.f};
                    s4 = __builtin_amdgcn_mfma_f32_16x16x32_bf16(qf[m][0], kf0, s4, 0, 0, 0);
                    s4 = __builtin_amdgcn_mfma_f32_16x16x32_bf16(qf[m][1], kf1, s4, 0, 0, 0);
                    int row00 = qb + w * 32 + m * 16 + lg * 4;
#pragma unroll
                    for (int r = 0; r < 4; r++)
                        sv[m][c][r] = (col > row00 + r) ? -1e30f : s4[r] * SCALE_LOG2E;
                }
            }

            // online softmax (max-reduce across 16 lanes; l-sum deferred to epilogue)
#pragma unroll
            for (int m = 0; m < 2; m++)
#pragma unroll
                for (int r = 0; r < 4; r++) {
                    float tm = fmaxf(fmaxf(sv[m][0][r], sv[m][1][r]),
                                     fmaxf(sv[m][2][r], sv[m][3][r]));
#pragma unroll
                    for (int d = 1; d < 16; d <<= 1) tm = fmaxf(tm, __shfl_xor(tm, d));
                    float mn = fmaxf(mrow[m][r], tm);
                    float alpha = exp2f(mrow[m][r] - mn);
                    mrow[m][r] = mn;
                    float ps = 0.f;
#pragma unroll
                    for (int c = 0; c < 4; c++) {
                        float pv = exp2f(sv[m][c][r] - mn);
                        sv[m][c][r] = pv;
                        ps += pv;
                    }
                    lpart[m][r] = lpart[m][r] * alpha + ps;
#pragma unroll
                    for (int cd = 0; cd < 4; cd++) o[m][cd][r] *= alpha;
                }

            // P -> LDS (wave-local)
#pragma unroll
            for (int m = 0; m < 2; m++)
#pragma unroll
                for (int c = 0; c < 4; c++)
#pragma unroll
                    for (int r = 0; r < 4; r++)
                        Ps[w][m * 16 + lg * 4 + r][c * 16 + l15] = f2bf(sv[m][c][r]);

            bf16x8 pf[2][2];
#pragma unroll
            for (int m = 0; m < 2; m++) {
                pf[m][0] = *(const bf16x8*)(&Ps[w][m * 16 + l15][lg * 8]);
                pf[m][1] = *(const bf16x8*)(&Ps[w][m * 16 + l15][32 + lg * 8]);
            }
#pragma unroll
            for (int cd = 0; cd < 4; cd++) {
                bf16x8 vf0 = *(const bf16x8*)(&Vs[cd * 16 + l15][lg * 8]);
                bf16x8 vf1 = *(const bf16x8*)(&Vs[cd * 16 + l15][32 + lg * 8]);
#pragma unroll
                for (int m = 0; m < 2; m++) {
                    o[m][cd] = __builtin_amdgcn_mfma_f32_16x16x32_bf16(pf[m][0], vf0, o[m][cd], 0, 0, 0);
                    o[m][cd] = __builtin_amdgcn_mfma_f32_16x16x32_bf16(pf[m][1], vf1, o[m][cd], 0, 0, 0);
                }
            }
        }
    }

    // epilogue: reduce deferred l-sum, normalize, write att [B*T][C] bf16
#pragma unroll
    for (int m = 0; m < 2; m++)
#pragma unroll
        for (int r = 0; r < 4; r++) {
            float ls = lpart[m][r];
#pragma unroll
            for (int d = 1; d < 16; d <<= 1) ls += __shfl_xor(ls, d);
            float inv = 1.0f / ls;
            int trow = qb + w * 32 + m * 16 + lg * 4 + r;
#pragma unroll
            for (int cd = 0; cd < 4; cd++) {
                int col = h * 64 + cd * 16 + l15;
                att[((size_t)(b * T_ + trow)) * C_ + col] = f2bf(o[m][cd][r] * inv);
            }
        }
}

extern "C" void kernel_launch(void* const* d_in, const int* in_sizes, int n_in,
                              void* d_out, int out_size, void* d_ws, size_t ws_size,
                              hipStream_t stream)
{
    const float* x      = (const float*)d_in[0];
    const float* W_qkv  = (const float*)d_in[1];
    const float* b_qkv  = (const float*)d_in[2];
    const float* W_proj = (const float*)d_in[3];
    const float* b_proj = (const float*)d_in[4];
    float* out = (float*)d_out;

    char* p = (char*)d_ws;
    unsigned short* xbf    = (unsigned short*)p; p += (size_t)8192 * 1024 * 2;  // reused as att out
    unsigned short* wqkvT  = (unsigned short*)p; p += (size_t)3072 * 1024 * 2;
    unsigned short* wprojT = (unsigned short*)p; p += (size_t)1024 * 1024 * 2;
    unsigned short* Qb     = (unsigned short*)p; p += (size_t)8192 * 1024 * 2;
    unsigned short* Kb     = (unsigned short*)p; p += (size_t)8192 * 1024 * 2;
    unsigned short* Vt     = (unsigned short*)p; p += (size_t)8192 * 1024 * 2;  // [B*H, 64, T]

    k_conv<<<8192, 256, 0, stream>>>(x, xbf, 8192 * 1024);
    k_transp<<<dim3(96, 32), 256, 0, stream>>>(W_qkv, wqkvT, 1024, 3072);
    k_transp<<<dim3(32, 32), 256, 0, stream>>>(W_proj, wprojT, 1024, 1024);
    k_gemm<0><<<dim3(24, 64), 256, 0, stream>>>(xbf, wqkvT, b_qkv, Qb, Kb, Vt, nullptr, 8192, 3072, 1024);
    k_attn<<<dim3(16, 64), 256, 0, stream>>>(Qb, Kb, Vt, xbf);
    k_gemm<1><<<dim3(8, 64), 256, 0, stream>>>(xbf, wprojT, b_proj, nullptr, nullptr, nullptr, out, 8192, 1024, 1024);
}

// Round 3
// 278.364 us; speedup vs baseline: 1.4543x; 1.2896x over previous
//
#include <hip/hip_runtime.h>

// CausalSelfAttention: B=4, T=2048, C=1024, H=16, HD=64
// Pipeline: x->bf16 | W->bf16^T | QKV GEMM (global_load_lds, V written transposed) |
//           flash attn (64-row q-tiles, paired for uniform cost) | proj GEMM

typedef __attribute__((ext_vector_type(8))) short bf16x8;
typedef __attribute__((ext_vector_type(4))) float f32x4;
typedef __attribute__((ext_vector_type(4))) int int4v;

#define B_ 4
#define T_ 2048
#define C_ 1024
#define H_ 16
#define HD_ 64
#define SCALE_LOG2E 0.18033688011112042f   // (1/8) * log2(e)

__device__ __forceinline__ unsigned short f2bf(float f) {
    union { float f; unsigned u; } c; c.f = f;
    unsigned u = c.u;
    u = u + 0x7FFFu + ((u >> 16) & 1u);   // RNE
    return (unsigned short)(u >> 16);
}

// ---------------- x f32 -> bf16 ----------------
__global__ __launch_bounds__(256) void k_conv(const float* __restrict__ in,
                                              unsigned short* __restrict__ out, int n) {
    int i = (blockIdx.x * 256 + threadIdx.x) * 4;
    if (i >= n) return;
    float4 v = *(const float4*)(in + i);
    unsigned short r[4] = { f2bf(v.x), f2bf(v.y), f2bf(v.z), f2bf(v.w) };
    *(unsigned long long*)(out + i) = *(const unsigned long long*)r;
}

// ---------------- W [R][Cin] f32 -> out [Cin][R] bf16 (transpose+convert) ----------------
__global__ __launch_bounds__(256) void k_transp(const float* __restrict__ in,
                                                unsigned short* __restrict__ out,
                                                int R, int Cin) {
    __shared__ float t[32][33];
    int bx = blockIdx.x, by = blockIdx.y;
    int j = threadIdx.x & 31, i0 = threadIdx.x >> 5;
#pragma unroll
    for (int k = 0; k < 4; k++) {
        int i = i0 + k * 8;
        t[i][j] = in[(size_t)(by * 32 + i) * Cin + bx * 32 + j];
    }
    __syncthreads();
#pragma unroll
    for (int k = 0; k < 4; k++) {
        int c = i0 + k * 8;
        out[(size_t)(bx * 32 + c) * R + by * 32 + j] = f2bf(t[j][c]);
    }
}

// ---------------- GEMM: D[M][N] = A[M][K] * BT[N][K]^T + bias ----------------
// m97 structure: global_load_lds width-16 staging, unpadded LDS, 2 barriers/K-step.
// MODE 0: scatter Q/K bf16 [B,H,T,64], V transposed -> Vt [B,H,64,T].  MODE 1: f32 out.
template<int MODE>
__global__ __launch_bounds__(256) void k_gemm(
    const unsigned short* __restrict__ A, const unsigned short* __restrict__ BT,
    const float* __restrict__ bias,
    unsigned short* __restrict__ Qb, unsigned short* __restrict__ Kb,
    unsigned short* __restrict__ Vt,
    float* __restrict__ out, int M, int N, int K)
{
    __shared__ unsigned short As[128][32];   // unpadded: global_load_lds needs linear dest
    __shared__ unsigned short Bs[128][32];
    const int tid = threadIdx.x;
    const int lane = tid & 63;
    const int wv = tid >> 6;
    const int wm = wv >> 1, wn = wv & 1;
    const int l15 = lane & 15, lg = lane >> 4;
    const int bm = blockIdx.y * 128, bn = blockIdx.x * 128;

    f32x4 acc[4][4];
#pragma unroll
    for (int m = 0; m < 4; m++)
#pragma unroll
        for (int n = 0; n < 4; n++) acc[m][n] = (f32x4){0.f, 0.f, 0.f, 0.f};

#if __has_builtin(__builtin_amdgcn_global_load_lds)
    const int rl = lane >> 2;            // 0..15 (row within 16-row chunk)
    const int cl = (lane & 3) * 8;       // 0,8,16,24
#else
    const int sr = tid >> 2;
    const int sc = (tid & 3) * 8;
#endif

    for (int k0 = 0; k0 < K; k0 += 32) {
#if __has_builtin(__builtin_amdgcn_global_load_lds)
#pragma unroll
        for (int i = 0; i < 2; i++) {
            int c = wv + i * 4;          // chunk 0..7 (16 rows each)
            __builtin_amdgcn_global_load_lds(
                (const __attribute__((address_space(1))) void*)
                    (&A[(size_t)(bm + c * 16 + rl) * K + k0 + cl]),
                (__attribute__((address_space(3))) void*)(&As[c * 16][0]), 16, 0, 0);
            __builtin_amdgcn_global_load_lds(
                (const __attribute__((address_space(1))) void*)
                    (&BT[(size_t)(bn + c * 16 + rl) * K + k0 + cl]),
                (__attribute__((address_space(3))) void*)(&Bs[c * 16][0]), 16, 0, 0);
        }
#else
#pragma unroll
        for (int rr = 0; rr < 128; rr += 64) {
            *(int4v*)(&As[sr + rr][sc]) = *(const int4v*)(&A[(size_t)(bm + sr + rr) * K + k0 + sc]);
            *(int4v*)(&Bs[sr + rr][sc]) = *(const int4v*)(&BT[(size_t)(bn + sr + rr) * K + k0 + sc]);
        }
#endif
        __syncthreads();
        bf16x8 af[4], bfr[4];
#pragma unroll
        for (int m = 0; m < 4; m++) af[m]  = *(const bf16x8*)(&As[wm * 64 + m * 16 + l15][lg * 8]);
#pragma unroll
        for (int n = 0; n < 4; n++) bfr[n] = *(const bf16x8*)(&Bs[wn * 64 + n * 16 + l15][lg * 8]);
        __builtin_amdgcn_s_setprio(1);
#pragma unroll
        for (int m = 0; m < 4; m++)
#pragma unroll
            for (int n = 0; n < 4; n++)
                acc[m][n] = __builtin_amdgcn_mfma_f32_16x16x32_bf16(af[m], bfr[n], acc[m][n], 0, 0, 0);
        __builtin_amdgcn_s_setprio(0);
        __syncthreads();
    }

#pragma unroll
    for (int m = 0; m < 4; m++) {
#pragma unroll
        for (int n = 0; n < 4; n++) {
            int col = bn + wn * 64 + n * 16 + l15;
            float bval = bias[col];
            int row0 = bm + wm * 64 + m * 16 + lg * 4;
            float vals[4];
#pragma unroll
            for (int r = 0; r < 4; r++) vals[r] = acc[m][n][r] + bval;
            if (MODE == 1) {
#pragma unroll
                for (int r = 0; r < 4; r++) out[(size_t)(row0 + r) * N + col] = vals[r];
            } else {
                int b = row0 >> 11, t0 = row0 & 2047;
                int which = col >> 10;
                int h = (col & 1023) >> 6, d = col & 63;
                if (which == 2) {
                    unsigned short pk[4];
#pragma unroll
                    for (int r = 0; r < 4; r++) pk[r] = f2bf(vals[r]);
                    *(unsigned long long*)(&Vt[((size_t)(b * H_ + h) * HD_ + d) * T_ + t0]) =
                        *(const unsigned long long*)pk;
                } else {
                    unsigned short* dst = which ? Kb : Qb;
#pragma unroll
                    for (int r = 0; r < 4; r++)
                        dst[((size_t)(b * H_ + h) * T_ + t0 + r) * HD_ + d] = f2bf(vals[r]);
                }
            }
        }
    }
}

// ---------------- Flash attention (causal) ----------------
// Q,K: [B*H, T, 64].  Vt: [B*H, 64, T].
// 64 q-rows per block-job (16 per wave); each block runs the pair (31-bx, bx)
// so every block costs exactly 33 k-tiles -> uniform runtime, steady occupancy.
__global__ __launch_bounds__(256) void k_attn(
    const unsigned short* __restrict__ Qb, const unsigned short* __restrict__ Kb,
    const unsigned short* __restrict__ Vt, unsigned short* __restrict__ att)
{
    __shared__ unsigned short Ks[64][72];       // [key][d]
    __shared__ unsigned short Vs[64][72];       // [d][key]  (straight copy from Vt)
    __shared__ unsigned short Ps[4][16][72];    // per-wave P tile [qrow][key]

    const int tid = threadIdx.x, lane = tid & 63, w = tid >> 6;
    const int l15 = lane & 15, lg = lane >> 4;
    const int bh = blockIdx.y;
    const int b = bh >> 4, h = bh & 15;
    const size_t kqbase = (size_t)bh * T_ * HD_;
    const size_t vtbase = (size_t)bh * HD_ * T_;

    const int r0 = tid >> 3;          // 0..31
    const int c8 = (tid & 7) * 8;

#pragma unroll 1
    for (int job = 0; job < 2; ++job) {
        const int qt = job ? (int)blockIdx.x : 31 - (int)blockIdx.x;
        const int qb = qt * 64;

        // Q fragments: wave w owns rows qb+w*16 .. +15
        bf16x8 qf[2];
#pragma unroll
        for (int s = 0; s < 2; s++)
            qf[s] = *(const bf16x8*)(Qb + kqbase +
                        (size_t)(qb + w * 16 + l15) * HD_ + s * 32 + lg * 8);

        f32x4 o[4];
        float mrow[4], lpart[4];
#pragma unroll
        for (int r = 0; r < 4; r++) { mrow[r] = -1e30f; lpart[r] = 0.f; }
#pragma unroll
        for (int c = 0; c < 4; c++) o[c] = (f32x4){0.f, 0.f, 0.f, 0.f};

        const int row00 = qb + w * 16 + lg * 4;

        // prefetch tile 0
        int4v kreg[2], vreg[2];
#pragma unroll
        for (int i = 0; i < 2; i++) {
            kreg[i] = *(const int4v*)(Kb + kqbase + (size_t)(r0 + i * 32) * HD_ + c8);
            vreg[i] = *(const int4v*)(Vt + vtbase + (size_t)(r0 + i * 32) * T_ + c8);
        }

        for (int kt = 0; kt <= qt; ++kt) {
            __syncthreads();                    // previous tile's consumers done
#pragma unroll
            for (int i = 0; i < 2; i++) {
                *(int4v*)(&Ks[r0 + i * 32][c8]) = kreg[i];
                *(int4v*)(&Vs[r0 + i * 32][c8]) = vreg[i];
            }
            if (kt < qt) {                      // issue next tile's loads early
                int nk = (kt + 1) * 64;
#pragma unroll
                for (int i = 0; i < 2; i++) {
                    kreg[i] = *(const int4v*)(Kb + kqbase + (size_t)(nk + r0 + i * 32) * HD_ + c8);
                    vreg[i] = *(const int4v*)(Vt + vtbase + (size_t)(r0 + i * 32) * T_ + nk + c8);
                }
            }
            __syncthreads();                    // LDS tile ready

            // S = Q K^T  (16 q-rows x 64 keys per wave)
            float sv[4][4];
            __builtin_amdgcn_s_setprio(1);
#pragma unroll
            for (int c = 0; c < 4; c++) {
                bf16x8 kf0 = *(const bf16x8*)(&Ks[c * 16 + l15][lg * 8]);
                bf16x8 kf1 = *(const bf16x8*)(&Ks[c * 16 + l15][32 + lg * 8]);
                f32x4 s4 = (f32x4){0.f, 0.f, 0.f, 0.f};
                s4 = __builtin_amdgcn_mfma_f32_16x16x32_bf16(qf[0], kf0, s4, 0, 0, 0);
                s4 = __builtin_amdgcn_mfma_f32_16x16x32_bf16(qf[1], kf1, s4, 0, 0, 0);
                int col = kt * 64 + c * 16 + l15;
#pragma unroll
                for (int r = 0; r < 4; r++)
                    sv[c][r] = (col > row00 + r) ? -1e30f : s4[r] * SCALE_LOG2E;
            }
            __builtin_amdgcn_s_setprio(0);

            // online softmax (max across 16 lanes; l-sum deferred to epilogue)
#pragma unroll
            for (int r = 0; r < 4; r++) {
                float tm = fmaxf(fmaxf(sv[0][r], sv[1][r]), fmaxf(sv[2][r], sv[3][r]));
#pragma unroll
                for (int d = 1; d < 16; d <<= 1) tm = fmaxf(tm, __shfl_xor(tm, d));
                float mn = fmaxf(mrow[r], tm);
                float alpha = exp2f(mrow[r] - mn);
                mrow[r] = mn;
                float ps = 0.f;
#pragma unroll
                for (int c = 0; c < 4; c++) {
                    float pv = exp2f(sv[c][r] - mn);
                    sv[c][r] = pv;
                    ps += pv;
                }
                lpart[r] = lpart[r] * alpha + ps;
#pragma unroll
                for (int cd = 0; cd < 4; cd++) o[cd][r] *= alpha;
            }

            // P -> LDS (wave-local; lgkmcnt orders write->read)
#pragma unroll
            for (int c = 0; c < 4; c++)
#pragma unroll
                for (int r = 0; r < 4; r++)
                    Ps[w][lg * 4 + r][c * 16 + l15] = f2bf(sv[c][r]);

            bf16x8 pf0 = *(const bf16x8*)(&Ps[w][l15][lg * 8]);
            bf16x8 pf1 = *(const bf16x8*)(&Ps[w][l15][32 + lg * 8]);
            __builtin_amdgcn_s_setprio(1);
#pragma unroll
            for (int cd = 0; cd < 4; cd++) {
                bf16x8 vf0 = *(const bf16x8*)(&Vs[cd * 16 + l15][lg * 8]);
                bf16x8 vf1 = *(const bf16x8*)(&Vs[cd * 16 + l15][32 + lg * 8]);
                o[cd] = __builtin_amdgcn_mfma_f32_16x16x32_bf16(pf0, vf0, o[cd], 0, 0, 0);
                o[cd] = __builtin_amdgcn_mfma_f32_16x16x32_bf16(pf1, vf1, o[cd], 0, 0, 0);
            }
            __builtin_amdgcn_s_setprio(0);
        }

        // epilogue: reduce deferred l-sum, normalize, write att [B*T][C] bf16
#pragma unroll
        for (int r = 0; r < 4; r++) {
            float ls = lpart[r];
#pragma unroll
            for (int d = 1; d < 16; d <<= 1) ls += __shfl_xor(ls, d);
            float inv = 1.0f / ls;
            int trow = row00 + r;
#pragma unroll
            for (int cd = 0; cd < 4; cd++) {
                int col = h * 64 + cd * 16 + l15;
                att[((size_t)(b * T_ + trow)) * C_ + col] = f2bf(o[cd][r] * inv);
            }
        }
    }
}

extern "C" void kernel_launch(void* const* d_in, const int* in_sizes, int n_in,
                              void* d_out, int out_size, void* d_ws, size_t ws_size,
                              hipStream_t stream)
{
    const float* x      = (const float*)d_in[0];
    const float* W_qkv  = (const float*)d_in[1];
    const float* b_qkv  = (const float*)d_in[2];
    const float* W_proj = (const float*)d_in[3];
    const float* b_proj = (const float*)d_in[4];
    float* out = (float*)d_out;

    char* p = (char*)d_ws;
    unsigned short* xbf    = (unsigned short*)p; p += (size_t)8192 * 1024 * 2;  // reused as att out
    unsigned short* wqkvT  = (unsigned short*)p; p += (size_t)3072 * 1024 * 2;
    unsigned short* wprojT = (unsigned short*)p; p += (size_t)1024 * 1024 * 2;
    unsigned short* Qb     = (unsigned short*)p; p += (size_t)8192 * 1024 * 2;
    unsigned short* Kb     = (unsigned short*)p; p += (size_t)8192 * 1024 * 2;
    unsigned short* Vt     = (unsigned short*)p; p += (size_t)8192 * 1024 * 2;  // [B*H, 64, T]

    k_conv<<<8192, 256, 0, stream>>>(x, xbf, 8192 * 1024);
    k_transp<<<dim3(96, 32), 256, 0, stream>>>(W_qkv, wqkvT, 1024, 3072);
    k_transp<<<dim3(32, 32), 256, 0, stream>>>(W_proj, wprojT, 1024, 1024);
    k_gemm<0><<<dim3(24, 64), 256, 0, stream>>>(xbf, wqkvT, b_qkv, Qb, Kb, Vt, nullptr, 8192, 3072, 1024);
    k_attn<<<dim3(16, 64), 256, 0, stream>>>(Qb, Kb, Vt, xbf);
    k_gemm<1><<<dim3(8, 64), 256, 0, stream>>>(xbf, wprojT, b_proj, nullptr, nullptr, nullptr, out, 8192, 1024, 1024);
}

// Round 4
// 233.946 us; speedup vs baseline: 1.7305x; 1.1899x over previous
//
#include <hip/hip_runtime.h>

// CausalSelfAttention: B=4, T=2048, C=1024, H=16, HD=64
// Pipeline: x->bf16 | W->bf16^T | QKV GEMM (global_load_lds, V written transposed) |
//           flash attn (swapped-QK^T in-register softmax) | proj GEMM

typedef __attribute__((ext_vector_type(8))) short bf16x8;
typedef __attribute__((ext_vector_type(4))) float f32x4;
typedef __attribute__((ext_vector_type(4))) int int4v;

#define B_ 4
#define T_ 2048
#define C_ 1024
#define H_ 16
#define HD_ 64
#define SCALE_LOG2E 0.18033688011112042f   // (1/8) * log2(e)

__device__ __forceinline__ unsigned short f2bf(float f) {
    union { float f; unsigned u; } c; c.f = f;
    unsigned u = c.u;
    u = u + 0x7FFFu + ((u >> 16) & 1u);   // RNE
    return (unsigned short)(u >> 16);
}

// ---------------- x f32 -> bf16 ----------------
__global__ __launch_bounds__(256) void k_conv(const float* __restrict__ in,
                                              unsigned short* __restrict__ out, int n) {
    int i = (blockIdx.x * 256 + threadIdx.x) * 4;
    if (i >= n) return;
    float4 v = *(const float4*)(in + i);
    unsigned short r[4] = { f2bf(v.x), f2bf(v.y), f2bf(v.z), f2bf(v.w) };
    *(unsigned long long*)(out + i) = *(const unsigned long long*)r;
}

// ---------------- W [R][Cin] f32 -> out [Cin][R] bf16 (transpose+convert) ----------------
__global__ __launch_bounds__(256) void k_transp(const float* __restrict__ in,
                                                unsigned short* __restrict__ out,
                                                int R, int Cin) {
    __shared__ float t[32][33];
    int bx = blockIdx.x, by = blockIdx.y;
    int j = threadIdx.x & 31, i0 = threadIdx.x >> 5;
#pragma unroll
    for (int k = 0; k < 4; k++) {
        int i = i0 + k * 8;
        t[i][j] = in[(size_t)(by * 32 + i) * Cin + bx * 32 + j];
    }
    __syncthreads();
#pragma unroll
    for (int k = 0; k < 4; k++) {
        int c = i0 + k * 8;
        out[(size_t)(bx * 32 + c) * R + by * 32 + j] = f2bf(t[j][c]);
    }
}

// ---------------- GEMM: D[M][N] = A[M][K] * BT[N][K]^T + bias ----------------
// m97 structure: global_load_lds width-16 staging, unpadded LDS, 2 barriers/K-step.
// MODE 0: scatter Q/K bf16 [B,H,T,64], V transposed -> Vt [B,H,64,T].  MODE 1: f32 out.
template<int MODE>
__global__ __launch_bounds__(256) void k_gemm(
    const unsigned short* __restrict__ A, const unsigned short* __restrict__ BT,
    const float* __restrict__ bias,
    unsigned short* __restrict__ Qb, unsigned short* __restrict__ Kb,
    unsigned short* __restrict__ Vt,
    float* __restrict__ out, int M, int N, int K)
{
    __shared__ unsigned short As[128][32];   // unpadded: global_load_lds needs linear dest
    __shared__ unsigned short Bs[128][32];
    const int tid = threadIdx.x;
    const int lane = tid & 63;
    const int wv = tid >> 6;
    const int wm = wv >> 1, wn = wv & 1;
    const int l15 = lane & 15, lg = lane >> 4;
    const int bm = blockIdx.y * 128, bn = blockIdx.x * 128;

    f32x4 acc[4][4];
#pragma unroll
    for (int m = 0; m < 4; m++)
#pragma unroll
        for (int n = 0; n < 4; n++) acc[m][n] = (f32x4){0.f, 0.f, 0.f, 0.f};

#if __has_builtin(__builtin_amdgcn_global_load_lds)
    const int rl = lane >> 2;            // 0..15 (row within 16-row chunk)
    const int cl = (lane & 3) * 8;       // 0,8,16,24
#else
    const int sr = tid >> 2;
    const int sc = (tid & 3) * 8;
#endif

    for (int k0 = 0; k0 < K; k0 += 32) {
#if __has_builtin(__builtin_amdgcn_global_load_lds)
#pragma unroll
        for (int i = 0; i < 2; i++) {
            int c = wv + i * 4;          // chunk 0..7 (16 rows each)
            __builtin_amdgcn_global_load_lds(
                (const __attribute__((address_space(1))) void*)
                    (&A[(size_t)(bm + c * 16 + rl) * K + k0 + cl]),
                (__attribute__((address_space(3))) void*)(&As[c * 16][0]), 16, 0, 0);
            __builtin_amdgcn_global_load_lds(
                (const __attribute__((address_space(1))) void*)
                    (&BT[(size_t)(bn + c * 16 + rl) * K + k0 + cl]),
                (__attribute__((address_space(3))) void*)(&Bs[c * 16][0]), 16, 0, 0);
        }
#else
#pragma unroll
        for (int rr = 0; rr < 128; rr += 64) {
            *(int4v*)(&As[sr + rr][sc]) = *(const int4v*)(&A[(size_t)(bm + sr + rr) * K + k0 + sc]);
            *(int4v*)(&Bs[sr + rr][sc]) = *(const int4v*)(&BT[(size_t)(bn + sr + rr) * K + k0 + sc]);
        }
#endif
        __syncthreads();
        bf16x8 af[4], bfr[4];
#pragma unroll
        for (int m = 0; m < 4; m++) af[m]  = *(const bf16x8*)(&As[wm * 64 + m * 16 + l15][lg * 8]);
#pragma unroll
        for (int n = 0; n < 4; n++) bfr[n] = *(const bf16x8*)(&Bs[wn * 64 + n * 16 + l15][lg * 8]);
        __builtin_amdgcn_s_setprio(1);
#pragma unroll
        for (int m = 0; m < 4; m++)
#pragma unroll
            for (int n = 0; n < 4; n++)
                acc[m][n] = __builtin_amdgcn_mfma_f32_16x16x32_bf16(af[m], bfr[n], acc[m][n], 0, 0, 0);
        __builtin_amdgcn_s_setprio(0);
        __syncthreads();
    }

#pragma unroll
    for (int m = 0; m < 4; m++) {
#pragma unroll
        for (int n = 0; n < 4; n++) {
            int col = bn + wn * 64 + n * 16 + l15;
            float bval = bias[col];
            int row0 = bm + wm * 64 + m * 16 + lg * 4;
            float vals[4];
#pragma unroll
            for (int r = 0; r < 4; r++) vals[r] = acc[m][n][r] + bval;
            if (MODE == 1) {
#pragma unroll
                for (int r = 0; r < 4; r++) out[(size_t)(row0 + r) * N + col] = vals[r];
            } else {
                int b = row0 >> 11, t0 = row0 & 2047;
                int which = col >> 10;
                int h = (col & 1023) >> 6, d = col & 63;
                if (which == 2) {
                    unsigned short pk[4];
#pragma unroll
                    for (int r = 0; r < 4; r++) pk[r] = f2bf(vals[r]);
                    *(unsigned long long*)(&Vt[((size_t)(b * H_ + h) * HD_ + d) * T_ + t0]) =
                        *(const unsigned long long*)pk;
                } else {
                    unsigned short* dst = which ? Kb : Qb;
#pragma unroll
                    for (int r = 0; r < 4; r++)
                        dst[((size_t)(b * H_ + h) * T_ + t0 + r) * HD_ + d] = f2bf(vals[r]);
                }
            }
        }
    }
}

// ---------------- Flash attention (causal), swapped-QK^T in-register softmax ----------
// Q,K: [B*H, T, 64].  Vt: [B*H, 64, T].
// 64 q-rows per block-job (16 per wave); block runs pair (31-bx, bx): uniform 33 tiles.
// Swapped MFMA: S^T = mfma(K,Q) puts q-row = lane&15 -> whole row lane-local;
// PV computes O^T = mfma(V^T, P). D-layout (m89): row=(lane>>4)*4+reg, col=lane&15.
__global__ __launch_bounds__(256) void k_attn(
    const unsigned short* __restrict__ Qb, const unsigned short* __restrict__ Kb,
    const unsigned short* __restrict__ Vt, unsigned short* __restrict__ att)
{
    __shared__ unsigned short Ks[64][72];       // [key][d]
    __shared__ unsigned short Vs[64][72];       // [d][key]  (straight copy from Vt)
    __shared__ unsigned short Ps[4][16][72];    // per-wave P tile [qrow][key]

    const int tid = threadIdx.x, lane = tid & 63, w = tid >> 6;
    const int l15 = lane & 15, lg = lane >> 4;
    const int bh = blockIdx.y;
    const int b = bh >> 4, h = bh & 15;
    const size_t kqbase = (size_t)bh * T_ * HD_;
    const size_t vtbase = (size_t)bh * HD_ * T_;

    const int r0 = tid >> 3;          // 0..31
    const int c8 = (tid & 7) * 8;

#pragma unroll 1
    for (int job = 0; job < 2; ++job) {
        const int qt = job ? (int)blockIdx.x : 31 - (int)blockIdx.x;
        const int qb = qt * 64;
        const int qrow = qb + w * 16 + l15;     // this lane's q-row (fixed all tiles)

        // Q fragments: B-operand, col = l15
        bf16x8 qf[2];
#pragma unroll
        for (int s = 0; s < 2; s++)
            qf[s] = *(const bf16x8*)(Qb + kqbase + (size_t)qrow * HD_ + s * 32 + lg * 8);

        f32x4 o[4];                   // o[cd][r] = O^T[d=cd*16+lg*4+r][q=l15]
        float m_run = -1e30f, l_run = 0.f;
#pragma unroll
        for (int c = 0; c < 4; c++) o[c] = (f32x4){0.f, 0.f, 0.f, 0.f};

        // prefetch tile 0
        int4v kreg[2], vreg[2];
#pragma unroll
        for (int i = 0; i < 2; i++) {
            kreg[i] = *(const int4v*)(Kb + kqbase + (size_t)(r0 + i * 32) * HD_ + c8);
            vreg[i] = *(const int4v*)(Vt + vtbase + (size_t)(r0 + i * 32) * T_ + c8);
        }

        for (int kt = 0; kt <= qt; ++kt) {
            __syncthreads();                    // previous tile's consumers done
#pragma unroll
            for (int i = 0; i < 2; i++) {
                *(int4v*)(&Ks[r0 + i * 32][c8]) = kreg[i];
                *(int4v*)(&Vs[r0 + i * 32][c8]) = vreg[i];
            }
            if (kt < qt) {                      // issue next tile's loads early (T14)
                int nk = (kt + 1) * 64;
#pragma unroll
                for (int i = 0; i < 2; i++) {
                    kreg[i] = *(const int4v*)(Kb + kqbase + (size_t)(nk + r0 + i * 32) * HD_ + c8);
                    vreg[i] = *(const int4v*)(Vt + vtbase + (size_t)(r0 + i * 32) * T_ + nk + c8);
                }
            }
            __syncthreads();                    // LDS tile ready

            // S^T = K Q^T : sv[c][r] = S[key=kt*64+c*16+lg*4+r][q=l15] (masked, log2-scaled)
            float sv[4][4];
            __builtin_amdgcn_s_setprio(1);
#pragma unroll
            for (int c = 0; c < 4; c++) {
                bf16x8 kf0 = *(const bf16x8*)(&Ks[c * 16 + l15][lg * 8]);
                bf16x8 kf1 = *(const bf16x8*)(&Ks[c * 16 + l15][32 + lg * 8]);
                f32x4 s4 = (f32x4){0.f, 0.f, 0.f, 0.f};
                s4 = __builtin_amdgcn_mfma_f32_16x16x32_bf16(kf0, qf[0], s4, 0, 0, 0);
                s4 = __builtin_amdgcn_mfma_f32_16x16x32_bf16(kf1, qf[1], s4, 0, 0, 0);
                int key0 = kt * 64 + c * 16 + lg * 4;
#pragma unroll
                for (int r = 0; r < 4; r++)
                    sv[c][r] = (key0 + r > qrow) ? -1e30f : s4[r] * SCALE_LOG2E;
            }
            __builtin_amdgcn_s_setprio(0);

            // in-register online softmax: whole q-row is lane-local across 4 lane-groups
            float tm = fmaxf(fmaxf(fmaxf(sv[0][0], sv[0][1]), fmaxf(sv[0][2], sv[0][3])),
                             fmaxf(fmaxf(sv[1][0], sv[1][1]), fmaxf(sv[1][2], sv[1][3])));
            tm = fmaxf(tm, fmaxf(fmaxf(fmaxf(sv[2][0], sv[2][1]), fmaxf(sv[2][2], sv[2][3])),
                                 fmaxf(fmaxf(sv[3][0], sv[3][1]), fmaxf(sv[3][2], sv[3][3]))));
            tm = fmaxf(tm, __shfl_xor(tm, 16));
            tm = fmaxf(tm, __shfl_xor(tm, 32));
            float mn = fmaxf(m_run, tm);
            float alpha = exp2f(m_run - mn);
            m_run = mn;

            float ps = 0.f;
            unsigned short pk[16];
#pragma unroll
            for (int c = 0; c < 4; c++)
#pragma unroll
                for (int r = 0; r < 4; r++) {
                    float pv = exp2f(sv[c][r] - mn);
                    ps += pv;
                    pk[c * 4 + r] = f2bf(pv);
                }
            l_run = l_run * alpha + ps;
#pragma unroll
            for (int cd = 0; cd < 4; cd++)
#pragma unroll
                for (int r = 0; r < 4; r++) o[cd][r] *= alpha;

            // P -> LDS (wave-local, packed 8B writes), then read as B-operand frags
#pragma unroll
            for (int c = 0; c < 4; c++)
                *(unsigned long long*)(&Ps[w][l15][c * 16 + lg * 4]) =
                    *(const unsigned long long*)(&pk[c * 4]);

            bf16x8 pf0 = *(const bf16x8*)(&Ps[w][l15][lg * 8]);
            bf16x8 pf1 = *(const bf16x8*)(&Ps[w][l15][32 + lg * 8]);
            __builtin_amdgcn_s_setprio(1);
#pragma unroll
            for (int cd = 0; cd < 4; cd++) {
                bf16x8 vf0 = *(const bf16x8*)(&Vs[cd * 16 + l15][lg * 8]);
                bf16x8 vf1 = *(const bf16x8*)(&Vs[cd * 16 + l15][32 + lg * 8]);
                o[cd] = __builtin_amdgcn_mfma_f32_16x16x32_bf16(vf0, pf0, o[cd], 0, 0, 0);
                o[cd] = __builtin_amdgcn_mfma_f32_16x16x32_bf16(vf1, pf1, o[cd], 0, 0, 0);
            }
            __builtin_amdgcn_s_setprio(0);
        }

        // epilogue: cross-lane l reduce (4 lane-groups share a q-row), normalize, store packed
        float ls = l_run;
        ls += __shfl_xor(ls, 16);
        ls += __shfl_xor(ls, 32);
        float inv = 1.0f / ls;
        const size_t rowbase = ((size_t)(b * T_ + qrow)) * C_ + h * 64;
#pragma unroll
        for (int cd = 0; cd < 4; cd++) {
            unsigned short ok[4];
#pragma unroll
            for (int r = 0; r < 4; r++) ok[r] = f2bf(o[cd][r] * inv);
            *(unsigned long long*)(&att[rowbase + cd * 16 + lg * 4]) =
                *(const unsigned long long*)ok;
        }
    }
}

extern "C" void kernel_launch(void* const* d_in, const int* in_sizes, int n_in,
                              void* d_out, int out_size, void* d_ws, size_t ws_size,
                              hipStream_t stream)
{
    const float* x      = (const float*)d_in[0];
    const float* W_qkv  = (const float*)d_in[1];
    const float* b_qkv  = (const float*)d_in[2];
    const float* W_proj = (const float*)d_in[3];
    const float* b_proj = (const float*)d_in[4];
    float* out = (float*)d_out;

    char* p = (char*)d_ws;
    unsigned short* xbf    = (unsigned short*)p; p += (size_t)8192 * 1024 * 2;  // reused as att out
    unsigned short* wqkvT  = (unsigned short*)p; p += (size_t)3072 * 1024 * 2;
    unsigned short* wprojT = (unsigned short*)p; p += (size_t)1024 * 1024 * 2;
    unsigned short* Qb     = (unsigned short*)p; p += (size_t)8192 * 1024 * 2;
    unsigned short* Kb     = (unsigned short*)p; p += (size_t)8192 * 1024 * 2;
    unsigned short* Vt     = (unsigned short*)p; p += (size_t)8192 * 1024 * 2;  // [B*H, 64, T]

    k_conv<<<8192, 256, 0, stream>>>(x, xbf, 8192 * 1024);
    k_transp<<<dim3(96, 32), 256, 0, stream>>>(W_qkv, wqkvT, 1024, 3072);
    k_transp<<<dim3(32, 32), 256, 0, stream>>>(W_proj, wprojT, 1024, 1024);
    k_gemm<0><<<dim3(24, 64), 256, 0, stream>>>(xbf, wqkvT, b_qkv, Qb, Kb, Vt, nullptr, 8192, 3072, 1024);
    k_attn<<<dim3(16, 64), 256, 0, stream>>>(Qb, Kb, Vt, xbf);
    k_gemm<1><<<dim3(8, 64), 256, 0, stream>>>(xbf, wprojT, b_proj, nullptr, nullptr, nullptr, out, 8192, 1024, 1024);
}